// Round 15
// baseline (327.456 us; speedup 1.0000x reference)
//
#include <hip/hip_runtime.h>
#include <hip/hip_bf16.h>

#define N_NODES 100000
#define N_EDGES 640000
#define DIM 128
#define N_LAYERS 3
#define N_GRAPHS 128
#define N_OUT 10
#define SCAN_BLK 1024  // elements per scan block (256 thr x 4)
#define N_SCAN_BLKS ((N_NODES + SCAN_BLK - 1) / SCAN_BLK)  // 98
#define PCHUNK 128     // rows per pool block
#define NXCD 8
#define RNODES (N_NODES / NXCD)     // 12500 nodes per dst-range
#define R_EST 98304                 // staging capacity per range (ints)
#define BE 1000                     // edges per bucket block (640 blocks exactly)
#define RK 40                       // blocks per range for hist/fill (grid 320)
#define GEMM_GRID 782               // ~2 chunks of 64 rows per block
#define SMASK 0x1FFFF               // 17-bit src mask (N_NODES < 2^17)

typedef _Float16 h4 __attribute__((ext_vector_type(4)));
typedef _Float16 h2 __attribute__((ext_vector_type(2)));
typedef _Float16 h8 __attribute__((ext_vector_type(8)));
typedef float f32x4 __attribute__((ext_vector_type(4)));

// ---------------- phase A: bucket edges by dst-range (packed s|d_local) ----------------

__global__ __launch_bounds__(256) void bucket_edges(const int* __restrict__ ei,
                                                    int* __restrict__ rangeCur,
                                                    unsigned int* __restrict__ staging) {
    __shared__ int hist[NXCD];
    __shared__ int base[NXCD];
    const int e0 = blockIdx.x * BE;
    if (threadIdx.x < NXCD) hist[threadIdx.x] = 0;
    __syncthreads();

    unsigned int pk[4]; int r[4];
    #pragma unroll
    for (int k = 0; k < 4; ++k) {
        int e = e0 + threadIdx.x + k * 256;
        if (e < e0 + BE) {
            int s = ei[e];
            int d = ei[N_EDGES + e];
            r[k] = d / RNODES;
            pk[k] = (unsigned int)s | ((unsigned int)(d - r[k] * RNODES) << 17);
            atomicAdd(&hist[r[k]], 1);
        } else r[k] = -1;
    }
    __syncthreads();
    if (threadIdx.x < NXCD) base[threadIdx.x] = atomicAdd(&rangeCur[threadIdx.x], hist[threadIdx.x]);
    __syncthreads();
    if (threadIdx.x < NXCD) hist[threadIdx.x] = 0;  // reuse as running cursor
    __syncthreads();

    #pragma unroll
    for (int k = 0; k < 4; ++k) {
        if (r[k] >= 0) {
            int idx = base[r[k]] + atomicAdd(&hist[r[k]], 1);
            staging[(size_t)r[k] * R_EST + idx] = pk[k];
        }
    }
}

// ---------------- phase B1: histogram (range-pinned: blockIdx&7 = range) ----------------

__global__ __launch_bounds__(256) void hist_pinned(const unsigned int* __restrict__ staging,
                                                   const int* __restrict__ rangeCur,
                                                   int* __restrict__ cnt) {
    const int g = blockIdx.x & (NXCD - 1);
    const int b = blockIdx.x >> 3;
    const int n = rangeCur[g];
    const unsigned int* st = staging + (size_t)g * R_EST;
    const int dbase = g * RNODES;
    for (int j = b * 256 + threadIdx.x; j < n; j += RK * 256)
        atomicAdd(&cnt[dbase + (st[j] >> 17)], 1);
}

// ---------------- exclusive scan (3 kernels) + fused dinv ----------------

__global__ void scan1(const int* __restrict__ cnt, int* __restrict__ off, int* __restrict__ bsum,
                      float* __restrict__ dinv) {
    __shared__ int tmp[256];
    int base = blockIdx.x * SCAN_BLK + threadIdx.x * 4;
    int c[4];
    #pragma unroll
    for (int k = 0; k < 4; ++k) c[k] = (base + k < N_NODES) ? cnt[base + k] : 0;
    #pragma unroll
    for (int k = 0; k < 4; ++k)
        if (base + k < N_NODES) dinv[base + k] = rsqrtf((float)(c[k] + 1));
    int tot = c[0] + c[1] + c[2] + c[3];
    tmp[threadIdx.x] = tot;
    __syncthreads();
    int val = tot;
    for (int d = 1; d < 256; d <<= 1) {
        int add = (threadIdx.x >= d) ? tmp[threadIdx.x - d] : 0;
        __syncthreads();
        val += add;
        tmp[threadIdx.x] = val;
        __syncthreads();
    }
    int ex = val - tot;
    int e1 = ex + c[0], e2 = e1 + c[1], e3 = e2 + c[2];
    if (base + 0 < N_NODES) off[base + 0] = ex;
    if (base + 1 < N_NODES) off[base + 1] = e1;
    if (base + 2 < N_NODES) off[base + 2] = e2;
    if (base + 3 < N_NODES) off[base + 3] = e3;
    if (threadIdx.x == 255) bsum[blockIdx.x] = val;
}

__global__ void scan2(int* __restrict__ bsum) {
    __shared__ int tmp[128];
    int t = threadIdx.x;
    int v = (t < N_SCAN_BLKS) ? bsum[t] : 0;
    int own = v;
    tmp[t] = v;
    __syncthreads();
    for (int d = 1; d < 128; d <<= 1) {
        int add = (t >= d) ? tmp[t - d] : 0;
        __syncthreads();
        v += add;
        tmp[t] = v;
        __syncthreads();
    }
    if (t < N_SCAN_BLKS) bsum[t] = v - own;  // exclusive
}

__global__ void scan3(int* __restrict__ off, const int* __restrict__ bsum) {
    int i = blockIdx.x * blockDim.x + threadIdx.x;
    if (i < N_NODES) off[i] += bsum[i / SCAN_BLK];
    if (i == 0) off[N_NODES] = N_EDGES;
}

// ---------------- phase B2: CSR fill (range-pinned) ----------------

__global__ __launch_bounds__(256) void fill_pinned(const unsigned int* __restrict__ staging,
                                                   const int* __restrict__ rangeCur,
                                                   const int* __restrict__ off,
                                                   int* __restrict__ cursor,
                                                   int* __restrict__ csr_src) {
    const int g = blockIdx.x & (NXCD - 1);
    const int b = blockIdx.x >> 3;
    const int n = rangeCur[g];
    const unsigned int* st = staging + (size_t)g * R_EST;
    const int dbase = g * RNODES;
    for (int j = b * 256 + threadIdx.x; j < n; j += RK * 256) {
        unsigned int v = st[j];
        int d = dbase + (int)(v >> 17);
        int pos = off[d] + atomicAdd(&cursor[d], 1);
        csr_src[pos] = (int)(v & SMASK);
    }
}

// ---------------- W prep: transpose + fp16 + XOR-swizzle ----------------

__global__ void wt_prep(const float* __restrict__ Ws, _Float16* __restrict__ wt) {
    int t = blockIdx.x * blockDim.x + threadIdx.x;  // (l, n, u): 3*128*32
    if (t >= N_LAYERS * DIM * 32) return;
    int u = t & 31;
    int n = (t >> 5) & 127;
    int l = t >> 12;
    const float* W = Ws + (size_t)l * DIM * DIM;
    int k0 = u * 4;
    h4 v;
    v.x = (_Float16)W[(k0 + 0) * DIM + n];
    v.y = (_Float16)W[(k0 + 1) * DIM + n];
    v.z = (_Float16)W[(k0 + 2) * DIM + n];
    v.w = (_Float16)W[(k0 + 3) * DIM + n];
    int du = u ^ (n & 31);
    ((h4*)wt)[(size_t)l * 4096 + n * 32 + du] = v;
}

// ---------------- MFMA dense transform (layer 0 only): out = dinv * (x @ W) ----------------
// R13 structure: LDS W + LDS 64-row input tile (h8-XOR-swizzled), f32 input.

__global__ __launch_bounds__(256) void gemm_mfma(const float* __restrict__ in,
                                                 const _Float16* __restrict__ wt,
                                                 const float* __restrict__ dinv,
                                                 _Float16* __restrict__ out) {
    __shared__ __align__(16) h4 Wl[4096];   // 32 KB swizzled W^T
    __shared__ __align__(16) h4 Hl[2048];   // 16 KB: 64 rows x 32 h4-units, h8-swizzled
    {
        const float4* src = (const float4*)wt;
        float4* dst = (float4*)Wl;
        #pragma unroll
        for (int i = 0; i < 8; ++i) dst[threadIdx.x + i * 256] = src[threadIdx.x + i * 256];
    }

    const int wave = threadIdx.x >> 6;
    const int lane = threadIdx.x & 63;
    const int row = lane & 15;
    const int g   = lane >> 4;
    const int hrow = wave * 16 + row;

    for (int c0 = blockIdx.x * 64; c0 < N_NODES; c0 += GEMM_GRID * 64) {
        __syncthreads();
        #pragma unroll
        for (int it = 0; it < 8; ++it) {
            int j = threadIdx.x + it * 256;
            int r = j >> 5, u4 = j & 31;
            int rs = c0 + r; if (rs > N_NODES - 1) rs = N_NODES - 1;
            float4 f = *(const float4*)(in + (size_t)rs * DIM + u4 * 4);
            h4 v; v.x = (_Float16)f.x; v.y = (_Float16)f.y;
            v.z = (_Float16)f.z; v.w = (_Float16)f.w;
            Hl[r * 32 + ((u4 >> 1) ^ (r & 15)) * 2 + (u4 & 1)] = v;
        }
        __syncthreads();

        f32x4 acc[8] = {};
        #pragma unroll
        for (int kc = 0; kc < 8; ++kc) {
            const h4 bfrag = Hl[hrow * 32 + ((kc * 2 + (g >> 1)) ^ (hrow & 15)) * 2 + (g & 1)];
            const int u = kc * 4 + g;
            #pragma unroll
            for (int nb = 0; nb < 8; ++nb) {
                const int n = nb * 16 + row;
                acc[nb] = __builtin_amdgcn_mfma_f32_16x16x16f16(Wl[n * 32 + (u ^ (n & 31))],
                                                                bfrag, acc[nb], 0, 0, 0);
            }
        }

        const int m = c0 + hrow;
        if (m < N_NODES) {
            const float di = dinv[m];
            _Float16* orow = out + (size_t)m * DIM;
            #pragma unroll
            for (int nb = 0; nb < 8; ++nb) {
                h4 v;
                v.x = (_Float16)(acc[nb].x * di); v.y = (_Float16)(acc[nb].y * di);
                v.z = (_Float16)(acc[nb].z * di); v.w = (_Float16)(acc[nb].w * di);
                ((h4*)orow)[nb * 4 + g] = v;
            }
        }
    }
}

// ---------------- FUSED: aggregate+bias+relu -> per-wave tile GEMM -> hw_out ----------------
// 512 threads = 8 waves x 16 nodes. Wave gathers its 16 rows into a private Hl slice
// (h8-XOR swizzle), then runs the verified R13 MFMA tile loop on its own rows (no barrier).

__global__ __launch_bounds__(512) void fused_agg_gemm(const _Float16* __restrict__ hw_in,
                                                      const float* __restrict__ dinv,
                                                      const int* __restrict__ off,
                                                      const int* __restrict__ csr_src,
                                                      const float* __restrict__ bias,
                                                      const _Float16* __restrict__ wt,
                                                      _Float16* __restrict__ hw_out) {
    __shared__ __align__(16) h4 Wl[4096];   // 32 KB swizzled W^T (next layer)
    __shared__ __align__(16) h4 Hl[4096];   // 32 KB: 128 rows x 32 h4, h8-swizzled
    {
        const float4* src = (const float4*)wt;
        float4* dst = (float4*)Wl;
        #pragma unroll
        for (int it = 0; it < 4; ++it) dst[threadIdx.x + it * 512] = src[threadIdx.x + it * 512];
    }
    __syncthreads();

    const int wave = threadIdx.x >> 6;   // 0..7
    const int lane = threadIdx.x & 63;
    const int grp    = lane >> 3;
    const int stream = grp & 3;
    const int half   = grp >> 2;
    const int sub    = lane & 7;
    const int idx8   = half * 8 + sub;
    const int c0 = blockIdx.x * 128;
    const h8* hw8 = (const h8*)hw_in;

    // ---- phase 1: gather wave's 16 nodes into Hl rows wave*16 .. +15 ----
    for (int n = 0; n < 16; ++n) {
        const int r = wave * 16 + n;
        const int i = c0 + r;
        if (i >= N_NODES) break;
        const int beg = off[i], end = off[i + 1];
        h8 acc = {};
        if (stream == 3) acc = hw8[(size_t)i * 16 + idx8];  // self-loop

        int j = beg + stream;
        for (; j + 4 < end; j += 8) {
            int s0 = csr_src[j];
            int s1 = csr_src[j + 4];
            h8 v0 = hw8[(size_t)s0 * 16 + idx8];
            h8 v1 = hw8[(size_t)s1 * 16 + idx8];
            #pragma unroll
            for (int p = 0; p < 4; ++p) {
                ((h2*)&acc)[p] += ((h2*)&v0)[p];
                ((h2*)&acc)[p] += ((h2*)&v1)[p];
            }
        }
        for (; j < end; j += 4) {
            int s0 = csr_src[j];
            h8 v0 = hw8[(size_t)s0 * 16 + idx8];
            #pragma unroll
            for (int p = 0; p < 4; ++p) ((h2*)&acc)[p] += ((h2*)&v0)[p];
        }

        unsigned int* au = (unsigned int*)&acc;
        #pragma unroll
        for (int p = 0; p < 4; ++p) {
            unsigned int o = __shfl_xor(au[p], 8);
            h2 a = *(h2*)&au[p]; a += *(h2*)&o; au[p] = *(unsigned int*)&a;
            o = __shfl_xor(au[p], 16);
            h2 b = *(h2*)&au[p]; b += *(h2*)&o; au[p] = *(unsigned int*)&b;
        }

        if (stream == 0) {
            const float di = dinv[i];
            const float4 b0 = *(const float4*)&bias[half * 64 + sub * 8];
            const float4 b1 = *(const float4*)&bias[half * 64 + sub * 8 + 4];
            h8 v;
            v[0] = (_Float16)fmaxf((float)acc[0] * di + b0.x, 0.0f);
            v[1] = (_Float16)fmaxf((float)acc[1] * di + b0.y, 0.0f);
            v[2] = (_Float16)fmaxf((float)acc[2] * di + b0.z, 0.0f);
            v[3] = (_Float16)fmaxf((float)acc[3] * di + b0.w, 0.0f);
            v[4] = (_Float16)fmaxf((float)acc[4] * di + b1.x, 0.0f);
            v[5] = (_Float16)fmaxf((float)acc[5] * di + b1.y, 0.0f);
            v[6] = (_Float16)fmaxf((float)acc[6] * di + b1.z, 0.0f);
            v[7] = (_Float16)fmaxf((float)acc[7] * di + b1.w, 0.0f);
            ((h8*)Hl)[r * 16 + (idx8 ^ (r & 15))] = v;   // wave-private slice
        }
    }

    // ---- phase 2: per-wave 16-row tile GEMM from own Hl rows (no barrier needed) ----
    const int row = lane & 15;
    const int g   = lane >> 4;
    const int hrow = wave * 16 + row;
    const int m = c0 + hrow;

    f32x4 acc[8] = {};
    #pragma unroll
    for (int kc = 0; kc < 8; ++kc) {
        const h4 bfrag = Hl[hrow * 32 + ((kc * 2 + (g >> 1)) ^ (hrow & 15)) * 2 + (g & 1)];
        const int u = kc * 4 + g;
        #pragma unroll
        for (int nb = 0; nb < 8; ++nb) {
            const int nn = nb * 16 + row;
            acc[nb] = __builtin_amdgcn_mfma_f32_16x16x16f16(Wl[nn * 32 + (u ^ (nn & 31))],
                                                            bfrag, acc[nb], 0, 0, 0);
        }
    }

    if (m < N_NODES) {
        const float di = dinv[m];   // next layer's source prescale
        _Float16* orow = hw_out + (size_t)m * DIM;
        #pragma unroll
        for (int nb = 0; nb < 8; ++nb) {
            h4 v;
            v.x = (_Float16)(acc[nb].x * di); v.y = (_Float16)(acc[nb].y * di);
            v.z = (_Float16)(acc[nb].z * di); v.w = (_Float16)(acc[nb].w * di);
            ((h4*)orow)[nb * 4 + g] = v;
        }
    }
}

// ---------------- plain gather (last layer): h3 = relu(agg + b) ----------------

__global__ __launch_bounds__(256) void gather_agg(const _Float16* __restrict__ hw,
                                                  const float* __restrict__ dinv,
                                                  const int* __restrict__ off,
                                                  const int* __restrict__ csr_src,
                                                  const float* __restrict__ bias,
                                                  _Float16* __restrict__ hout) {
    const int i = (blockIdx.x * blockDim.x + threadIdx.x) >> 6;  // node = wave id
    if (i >= N_NODES) return;
    const int lane = threadIdx.x & 63;
    const int grp    = lane >> 3;
    const int stream = grp & 3;
    const int half   = grp >> 2;
    const int sub    = lane & 7;
    const int idx8   = half * 8 + sub;
    const h8* hw8 = (const h8*)hw;

    const int beg = off[i], end = off[i + 1];
    h8 acc = {};

    if (stream == 3) acc = hw8[(size_t)i * 16 + idx8];

    int j = beg + stream;
    for (; j + 4 < end; j += 8) {
        int s0 = csr_src[j];
        int s1 = csr_src[j + 4];
        h8 v0 = hw8[(size_t)s0 * 16 + idx8];
        h8 v1 = hw8[(size_t)s1 * 16 + idx8];
        #pragma unroll
        for (int p = 0; p < 4; ++p) {
            ((h2*)&acc)[p] += ((h2*)&v0)[p];
            ((h2*)&acc)[p] += ((h2*)&v1)[p];
        }
    }
    for (; j < end; j += 4) {
        int s0 = csr_src[j];
        h8 v0 = hw8[(size_t)s0 * 16 + idx8];
        #pragma unroll
        for (int p = 0; p < 4; ++p) ((h2*)&acc)[p] += ((h2*)&v0)[p];
    }

    unsigned int* au = (unsigned int*)&acc;
    #pragma unroll
    for (int p = 0; p < 4; ++p) {
        unsigned int o = __shfl_xor(au[p], 8);
        h2 a = *(h2*)&au[p]; a += *(h2*)&o; au[p] = *(unsigned int*)&a;
        o = __shfl_xor(au[p], 16);
        h2 b = *(h2*)&au[p]; b += *(h2*)&o; au[p] = *(unsigned int*)&b;
    }

    if (stream == 0) {
        const float di = dinv[i];
        const float4 b0 = *(const float4*)&bias[half * 64 + sub * 8];
        const float4 b1 = *(const float4*)&bias[half * 64 + sub * 8 + 4];
        h8 v;
        v[0] = (_Float16)fmaxf((float)acc[0] * di + b0.x, 0.0f);
        v[1] = (_Float16)fmaxf((float)acc[1] * di + b0.y, 0.0f);
        v[2] = (_Float16)fmaxf((float)acc[2] * di + b0.z, 0.0f);
        v[3] = (_Float16)fmaxf((float)acc[3] * di + b0.w, 0.0f);
        v[4] = (_Float16)fmaxf((float)acc[4] * di + b1.x, 0.0f);
        v[5] = (_Float16)fmaxf((float)acc[5] * di + b1.y, 0.0f);
        v[6] = (_Float16)fmaxf((float)acc[6] * di + b1.z, 0.0f);
        v[7] = (_Float16)fmaxf((float)acc[7] * di + b1.w, 0.0f);
        ((h8*)hout)[(size_t)i * 16 + idx8] = v;
    }
}

// ---------------- chunked segmented pool (batch sorted) ----------------

__global__ __launch_bounds__(256) void pool_chunk(const _Float16* __restrict__ h,
                                                  const int* __restrict__ batch,
                                                  float* __restrict__ pooled) {
    const int base = blockIdx.x * PCHUNK;
    const int t = threadIdx.x;
    const int lane4 = t & 31;
    const int rgrp = t >> 5;
    const h4* hp = (const h4*)h;

    float a0 = 0.f, a1 = 0.f, a2 = 0.f, a3 = 0.f;
    int cur = -1;
    const int rend = (base + PCHUNK < N_NODES) ? base + PCHUNK : N_NODES;
    for (int r = base + rgrp; r < rend; r += 8) {
        int b = batch[r];
        if (b != cur) {
            if (cur >= 0) {
                float* pp = &pooled[cur * DIM + lane4 * 4];
                atomicAdd(pp + 0, a0); atomicAdd(pp + 1, a1);
                atomicAdd(pp + 2, a2); atomicAdd(pp + 3, a3);
            }
            cur = b; a0 = a1 = a2 = a3 = 0.f;
        }
        h4 v = hp[(size_t)r * 32 + lane4];
        a0 += (float)v.x; a1 += (float)v.y; a2 += (float)v.z; a3 += (float)v.w;
    }
    if (cur >= 0) {
        float* pp = &pooled[cur * DIM + lane4 * 4];
        atomicAdd(pp + 0, a0); atomicAdd(pp + 1, a1);
        atomicAdd(pp + 2, a2); atomicAdd(pp + 3, a3);
    }
}

// ---------------- head ----------------

__global__ void mlp_head(const float* __restrict__ pooled, const float* __restrict__ Wm,
                         const float* __restrict__ bm, float* __restrict__ out) {
    int t = blockIdx.x * blockDim.x + threadIdx.x;
    if (t >= N_GRAPHS * N_OUT) return;
    int b = t / N_OUT;
    int o = t % N_OUT;
    float acc = bm[o];
    #pragma unroll 8
    for (int k = 0; k < DIM; ++k) acc += pooled[b * DIM + k] * Wm[k * N_OUT + o];
    out[t] = acc;
}

// ---------------- launch ----------------

extern "C" void kernel_launch(void* const* d_in, const int* in_sizes, int n_in,
                              void* d_out, int out_size, void* d_ws, size_t ws_size,
                              hipStream_t stream) {
    const float* x     = (const float*)d_in[0];
    const int*   ei    = (const int*)d_in[1];
    const int*   batch = (const int*)d_in[2];
    const float* Ws    = (const float*)d_in[3];
    const float* bs    = (const float*)d_in[4];
    const float* Wm    = (const float*)d_in[5];
    const float* bm    = (const float*)d_in[6];
    float* out = (float*)d_out;

    // workspace carve-up (16B aligned; cnt+cursor+rangeCur adjacent for one memset)
    char* p = (char*)d_ws;
    int*          cnt      = (int*)p;          p += N_NODES * 4;
    int*          cursor   = (int*)p;          p += N_NODES * 4;
    int*          rangeCur = (int*)p;          p += 16 * 4;
    float*        dinv     = (float*)p;        p += N_NODES * 4;
    int*          csr_off  = (int*)p;          p += (N_NODES + 16) * 4;
    int*          bsum     = (int*)p;          p += 128 * 4;
    _Float16*     wt       = (_Float16*)p;     p += (size_t)N_LAYERS * DIM * DIM * 2;
    int*          csr_src  = (int*)p;          p += (size_t)N_EDGES * 4;
    unsigned int* staging  = (unsigned int*)p; p += (size_t)NXCD * R_EST * 4;
    _Float16*     bufA     = (_Float16*)p;     p += (size_t)N_NODES * DIM * 2;  // hw (prescaled)
    _Float16*     bufB     = (_Float16*)p;     p += (size_t)N_NODES * DIM * 2;  // hw / h3
    float*        pooled   = (float*)p;        p += N_GRAPHS * DIM * 4;

    const int nnode_blk = (N_NODES + 255) / 256;

    hipMemsetAsync(cnt, 0, N_NODES * 8 + 16 * 4, stream);  // cnt + cursor + rangeCur
    hipMemsetAsync(pooled, 0, N_GRAPHS * DIM * 4, stream);

    bucket_edges<<<N_EDGES / BE, 256, 0, stream>>>(ei, rangeCur, staging);
    wt_prep<<<(N_LAYERS * DIM * 32 + 255) / 256, 256, 0, stream>>>(Ws, wt);

    hist_pinned<<<NXCD * RK, 256, 0, stream>>>(staging, rangeCur, cnt);

    scan1<<<N_SCAN_BLKS, 256, 0, stream>>>(cnt, csr_off, bsum, dinv);
    scan2<<<1, 128, 0, stream>>>(bsum);
    scan3<<<nnode_blk, 256, 0, stream>>>(csr_off, bsum);

    fill_pinned<<<NXCD * RK, 256, 0, stream>>>(staging, rangeCur, csr_off, cursor, csr_src);

    const int fused_grid = (N_NODES + 127) / 128;        // 782
    const int gather_grid = (N_NODES * 64 + 255) / 256;  // one wave per node

    // layer 0 transform: x -> hw0 (bufA)
    gemm_mfma<<<GEMM_GRID, 256, 0, stream>>>(x, wt, dinv, bufA);
    // fused layer 1: agg(hw0)+b0+relu -> @W1*dinv -> hw1 (bufB)
    fused_agg_gemm<<<fused_grid, 512, 0, stream>>>(bufA, dinv, csr_off, csr_src,
                                                   bs, wt + (size_t)1 * DIM * DIM, bufB);
    // fused layer 2: agg(hw1)+b1+relu -> @W2*dinv -> hw2 (bufA)
    fused_agg_gemm<<<fused_grid, 512, 0, stream>>>(bufB, dinv, csr_off, csr_src,
                                                   bs + DIM, wt + (size_t)2 * DIM * DIM, bufA);
    // final aggregate: h3 (bufB)
    gather_agg<<<gather_grid, 256, 0, stream>>>(bufA, dinv, csr_off, csr_src,
                                                bs + 2 * DIM, bufB);

    pool_chunk<<<(N_NODES + PCHUNK - 1) / PCHUNK, 256, 0, stream>>>(bufB, batch, pooled);
    mlp_head<<<(N_GRAPHS * N_OUT + 255) / 256, 256, 0, stream>>>(pooled, Wm, bm, out);
}

// Round 16
// 284.269 us; speedup vs baseline: 1.1519x; 1.1519x over previous
//
#include <hip/hip_runtime.h>
#include <hip/hip_bf16.h>

#define N_NODES 100000
#define N_EDGES 640000
#define DIM 128
#define N_LAYERS 3
#define N_GRAPHS 128
#define N_OUT 10
#define SCAN_BLK 1024  // elements per scan block (256 thr x 4)
#define N_SCAN_BLKS ((N_NODES + SCAN_BLK - 1) / SCAN_BLK)  // 98
#define PCHUNK 128     // rows per pool block
#define NXCD 8
#define RNODES (N_NODES / NXCD)     // 12500 nodes per dst-range
#define R_EST 98304                 // staging capacity per range
#define BE 1000                     // edges per bucket block (640 blocks exactly)
#define RK 40                       // blocks per range for hist/fill (grid 320)
#define GEMM_GRID 512

typedef _Float16 h4 __attribute__((ext_vector_type(4)));
typedef _Float16 h2 __attribute__((ext_vector_type(2)));
typedef _Float16 h8 __attribute__((ext_vector_type(8)));
typedef float f32x4 __attribute__((ext_vector_type(4)));

// ---------------- phase A: bucket edges by dst-range ----------------

__global__ __launch_bounds__(256) void bucket_edges(const int* __restrict__ ei,
                                                    int* __restrict__ rangeCur,
                                                    int2* __restrict__ staging) {
    __shared__ int hist[NXCD];
    __shared__ int base[NXCD];
    const int e0 = blockIdx.x * BE;
    if (threadIdx.x < NXCD) hist[threadIdx.x] = 0;
    __syncthreads();

    int s[4], d[4], r[4];
    #pragma unroll
    for (int k = 0; k < 4; ++k) {
        int e = e0 + threadIdx.x + k * 256;
        if (e < e0 + BE) {
            s[k] = ei[e];
            d[k] = ei[N_EDGES + e];
            r[k] = d[k] / RNODES;
            atomicAdd(&hist[r[k]], 1);
        } else r[k] = -1;
    }
    __syncthreads();
    if (threadIdx.x < NXCD) base[threadIdx.x] = atomicAdd(&rangeCur[threadIdx.x], hist[threadIdx.x]);
    __syncthreads();
    if (threadIdx.x < NXCD) hist[threadIdx.x] = 0;  // reuse as running cursor
    __syncthreads();

    #pragma unroll
    for (int k = 0; k < 4; ++k) {
        if (r[k] >= 0) {
            int idx = base[r[k]] + atomicAdd(&hist[r[k]], 1);
            staging[(size_t)r[k] * R_EST + idx] = make_int2(s[k], d[k]);
        }
    }
}

// ---------------- phase B1: histogram (range-pinned: blockIdx&7 = range) ----------------

__global__ __launch_bounds__(256) void hist_pinned(const int2* __restrict__ staging,
                                                   const int* __restrict__ rangeCur,
                                                   int* __restrict__ cnt) {
    const int g = blockIdx.x & (NXCD - 1);
    const int b = blockIdx.x >> 3;
    const int n = rangeCur[g];
    const int2* st = staging + (size_t)g * R_EST;
    for (int j = b * 256 + threadIdx.x; j < n; j += RK * 256)
        atomicAdd(&cnt[st[j].y], 1);
}

// ---------------- exclusive scan (3 kernels) + fused dinv ----------------

__global__ void scan1(const int* __restrict__ cnt, int* __restrict__ off, int* __restrict__ bsum,
                      float* __restrict__ dinv) {
    __shared__ int tmp[256];
    int base = blockIdx.x * SCAN_BLK + threadIdx.x * 4;
    int c[4];
    #pragma unroll
    for (int k = 0; k < 4; ++k) c[k] = (base + k < N_NODES) ? cnt[base + k] : 0;
    #pragma unroll
    for (int k = 0; k < 4; ++k)
        if (base + k < N_NODES) dinv[base + k] = rsqrtf((float)(c[k] + 1));
    int tot = c[0] + c[1] + c[2] + c[3];
    tmp[threadIdx.x] = tot;
    __syncthreads();
    int val = tot;
    for (int d = 1; d < 256; d <<= 1) {
        int add = (threadIdx.x >= d) ? tmp[threadIdx.x - d] : 0;
        __syncthreads();
        val += add;
        tmp[threadIdx.x] = val;
        __syncthreads();
    }
    int ex = val - tot;
    int e1 = ex + c[0], e2 = e1 + c[1], e3 = e2 + c[2];
    if (base + 0 < N_NODES) off[base + 0] = ex;
    if (base + 1 < N_NODES) off[base + 1] = e1;
    if (base + 2 < N_NODES) off[base + 2] = e2;
    if (base + 3 < N_NODES) off[base + 3] = e3;
    if (threadIdx.x == 255) bsum[blockIdx.x] = val;
}

__global__ void scan2(int* __restrict__ bsum) {
    __shared__ int tmp[128];
    int t = threadIdx.x;
    int v = (t < N_SCAN_BLKS) ? bsum[t] : 0;
    int own = v;
    tmp[t] = v;
    __syncthreads();
    for (int d = 1; d < 128; d <<= 1) {
        int add = (t >= d) ? tmp[t - d] : 0;
        __syncthreads();
        v += add;
        tmp[t] = v;
        __syncthreads();
    }
    if (t < N_SCAN_BLKS) bsum[t] = v - own;  // exclusive
}

__global__ void scan3(int* __restrict__ off, const int* __restrict__ bsum) {
    int i = blockIdx.x * blockDim.x + threadIdx.x;
    if (i < N_NODES) off[i] += bsum[i / SCAN_BLK];
    if (i == 0) off[N_NODES] = N_EDGES;
}

// ---------------- phase B2: CSR fill (range-pinned) ----------------

__global__ __launch_bounds__(256) void fill_pinned(const int2* __restrict__ staging,
                                                   const int* __restrict__ rangeCur,
                                                   const int* __restrict__ off,
                                                   int* __restrict__ cursor,
                                                   int* __restrict__ csr_src) {
    const int g = blockIdx.x & (NXCD - 1);
    const int b = blockIdx.x >> 3;
    const int n = rangeCur[g];
    const int2* st = staging + (size_t)g * R_EST;
    for (int j = b * 256 + threadIdx.x; j < n; j += RK * 256) {
        int2 sd = st[j];
        int pos = off[sd.y] + atomicAdd(&cursor[sd.y], 1);
        csr_src[pos] = sd.x;
    }
}

// ---------------- W prep: transpose + fp16 + XOR-swizzle ----------------

__global__ void wt_prep(const float* __restrict__ Ws, _Float16* __restrict__ wt) {
    int t = blockIdx.x * blockDim.x + threadIdx.x;  // (l, n, u): 3*128*32
    if (t >= N_LAYERS * DIM * 32) return;
    int u = t & 31;
    int n = (t >> 5) & 127;
    int l = t >> 12;
    const float* W = Ws + (size_t)l * DIM * DIM;
    int k0 = u * 4;
    h4 v;
    v.x = (_Float16)W[(k0 + 0) * DIM + n];
    v.y = (_Float16)W[(k0 + 1) * DIM + n];
    v.z = (_Float16)W[(k0 + 2) * DIM + n];
    v.w = (_Float16)W[(k0 + 3) * DIM + n];
    int du = u ^ (n & 31);
    ((h4*)wt)[(size_t)l * 4096 + n * 32 + du] = v;
}

// ---------------- MFMA dense transform: out = dinv * (in @ W) ----------------
// Persistent pipelined: grid 512, W staged once/block, grid-stride over chunks,
// next chunk's 8 bfrag loads issued before current chunk's 64-MFMA loop.

__device__ __forceinline__ h4 loadfrag(const _Float16* p) { return *(const h4*)p; }
__device__ __forceinline__ h4 loadfrag(const float* p) {
    float4 f = *(const float4*)p;
    h4 v; v.x = (_Float16)f.x; v.y = (_Float16)f.y; v.z = (_Float16)f.z; v.w = (_Float16)f.w;
    return v;
}

template<typename TIN>
__global__ __launch_bounds__(256) void gemm_mfma(const TIN* __restrict__ in,
                                                 const _Float16* __restrict__ wt,
                                                 const float* __restrict__ dinv,
                                                 _Float16* __restrict__ out) {
    __shared__ h4 Wl[4096];  // 32 KB swizzled W^T
    {
        const float4* src = (const float4*)wt;
        float4* dst = (float4*)Wl;
        #pragma unroll
        for (int i = 0; i < 8; ++i) dst[threadIdx.x + i * 256] = src[threadIdx.x + i * 256];
    }
    __syncthreads();

    const int wave = threadIdx.x >> 6;
    const int lane = threadIdx.x & 63;
    const int row = lane & 15;   // m-offset (B col) / n-offset (A row)
    const int g   = lane >> 4;   // k-group
    const int STEP = GEMM_GRID * 64;

    // --- preload chunk 0 ---
    int c0 = blockIdx.x * 64;
    h4 bf[8];
    float di = 0.f;
    {
        int m0 = c0 + wave * 16;
        if (c0 < N_NODES) {
            const TIN* ar = in + (size_t)(m0 + row) * DIM;
            di = dinv[m0 + row];
            #pragma unroll
            for (int kc = 0; kc < 8; ++kc) bf[kc] = loadfrag(ar + kc * 16 + g * 4);
        }
    }

    for (; c0 < N_NODES; c0 += STEP) {
        // --- issue next chunk's loads (overlap with MFMA below) ---
        const int c1 = c0 + STEP;
        h4 bf2[8];
        float di2 = 0.f;
        if (c1 < N_NODES) {
            int m1 = c1 + wave * 16;
            const TIN* ar2 = in + (size_t)(m1 + row) * DIM;
            di2 = dinv[m1 + row];
            #pragma unroll
            for (int kc = 0; kc < 8; ++kc) bf2[kc] = loadfrag(ar2 + kc * 16 + g * 4);
        }

        // --- compute current chunk ---
        {
            f32x4 acc[8] = {};  // 8 n-tiles of 16 cols
            #pragma unroll
            for (int kc = 0; kc < 8; ++kc) {
                const int u = kc * 4 + g;
                #pragma unroll
                for (int nb = 0; nb < 8; ++nb) {
                    const int n = nb * 16 + row;
                    const h4 afrag = Wl[n * 32 + (u ^ (n & 31))];  // A[n][k..k+3]
                    acc[nb] = __builtin_amdgcn_mfma_f32_16x16x16f16(afrag, bf[kc], acc[nb], 0, 0, 0);
                }
            }
            _Float16* orow = out + (size_t)(c0 + wave * 16 + row) * DIM;
            #pragma unroll
            for (int nb = 0; nb < 8; ++nb) {
                h4 v;
                v.x = (_Float16)(acc[nb].x * di); v.y = (_Float16)(acc[nb].y * di);
                v.z = (_Float16)(acc[nb].z * di); v.w = (_Float16)(acc[nb].w * di);
                ((h4*)orow)[nb * 4 + g] = v;
            }
        }

        // --- rotate pipeline ---
        #pragma unroll
        for (int kc = 0; kc < 8; ++kc) bf[kc] = bf2[kc];
        di = di2;
    }
}

// ---------------- fused aggregate + scale + bias + relu ----------------
// hw holds dinv_s-prescaled rows; pure packed-fp16 adds, final scale by dinv_d.
// 8 groups of 8 lanes: stream = grp&3, half = grp>>2; 128B half-row per group.

__global__ __launch_bounds__(256) void gather_agg(const _Float16* __restrict__ hw,
                                                  const float* __restrict__ dinv,
                                                  const int* __restrict__ off,
                                                  const int* __restrict__ csr_src,
                                                  const float* __restrict__ bias,
                                                  _Float16* __restrict__ hout) {
    const int i = (blockIdx.x * blockDim.x + threadIdx.x) >> 6;  // node = wave id
    if (i >= N_NODES) return;
    const int lane = threadIdx.x & 63;
    const int grp    = lane >> 3;   // 0..7
    const int stream = grp & 3;     // edge stream
    const int half   = grp >> 2;    // row half
    const int sub    = lane & 7;    // h8 unit within half
    const int idx8   = half * 8 + sub;   // h8 index in row (16 per row)
    const h8* hw8 = (const h8*)hw;

    const int beg = off[i], end = off[i + 1];
    h8 acc = {};

    if (stream == 3) acc = hw8[(size_t)i * 16 + idx8];  // self-loop: += hw'_i

    int j = beg + stream;
    for (; j + 4 < end; j += 8) {
        int s0 = csr_src[j];
        int s1 = csr_src[j + 4];
        h8 v0 = hw8[(size_t)s0 * 16 + idx8];
        h8 v1 = hw8[(size_t)s1 * 16 + idx8];
        #pragma unroll
        for (int p = 0; p < 4; ++p) {
            ((h2*)&acc)[p] += ((h2*)&v0)[p];
            ((h2*)&acc)[p] += ((h2*)&v1)[p];
        }
    }
    for (; j < end; j += 4) {
        int s0 = csr_src[j];
        h8 v0 = hw8[(size_t)s0 * 16 + idx8];
        #pragma unroll
        for (int p = 0; p < 4; ++p) ((h2*)&acc)[p] += ((h2*)&v0)[p];
    }

    // packed fp16 reduce across the 4 streams (lane bits 3,4)
    unsigned int* au = (unsigned int*)&acc;
    #pragma unroll
    for (int p = 0; p < 4; ++p) {
        unsigned int o = __shfl_xor(au[p], 8);
        h2 a = *(h2*)&au[p]; a += *(h2*)&o; au[p] = *(unsigned int*)&a;
        o = __shfl_xor(au[p], 16);
        h2 b = *(h2*)&au[p]; b += *(h2*)&o; au[p] = *(unsigned int*)&b;
    }

    if (stream == 0) {  // grp 0 (half 0) and grp 4 (half 1) write their half
        const float di = dinv[i];
        const float4 b0 = *(const float4*)&bias[half * 64 + sub * 8];
        const float4 b1 = *(const float4*)&bias[half * 64 + sub * 8 + 4];
        h8 v;
        v[0] = (_Float16)fmaxf((float)acc[0] * di + b0.x, 0.0f);
        v[1] = (_Float16)fmaxf((float)acc[1] * di + b0.y, 0.0f);
        v[2] = (_Float16)fmaxf((float)acc[2] * di + b0.z, 0.0f);
        v[3] = (_Float16)fmaxf((float)acc[3] * di + b0.w, 0.0f);
        v[4] = (_Float16)fmaxf((float)acc[4] * di + b1.x, 0.0f);
        v[5] = (_Float16)fmaxf((float)acc[5] * di + b1.y, 0.0f);
        v[6] = (_Float16)fmaxf((float)acc[6] * di + b1.z, 0.0f);
        v[7] = (_Float16)fmaxf((float)acc[7] * di + b1.w, 0.0f);
        ((h8*)hout)[(size_t)i * 16 + idx8] = v;
    }
}

// ---------------- chunked segmented pool (batch sorted) ----------------

__global__ __launch_bounds__(256) void pool_chunk(const _Float16* __restrict__ h,
                                                  const int* __restrict__ batch,
                                                  float* __restrict__ pooled) {
    const int base = blockIdx.x * PCHUNK;
    const int t = threadIdx.x;
    const int lane4 = t & 31;    // dims lane4*4 .. +3
    const int rgrp = t >> 5;     // 0..7
    const h4* hp = (const h4*)h; // row stride 32

    float a0 = 0.f, a1 = 0.f, a2 = 0.f, a3 = 0.f;
    int cur = -1;
    const int rend = (base + PCHUNK < N_NODES) ? base + PCHUNK : N_NODES;
    for (int r = base + rgrp; r < rend; r += 8) {
        int b = batch[r];
        if (b != cur) {
            if (cur >= 0) {
                float* pp = &pooled[cur * DIM + lane4 * 4];
                atomicAdd(pp + 0, a0); atomicAdd(pp + 1, a1);
                atomicAdd(pp + 2, a2); atomicAdd(pp + 3, a3);
            }
            cur = b; a0 = a1 = a2 = a3 = 0.f;
        }
        h4 v = hp[(size_t)r * 32 + lane4];
        a0 += (float)v.x; a1 += (float)v.y; a2 += (float)v.z; a3 += (float)v.w;
    }
    if (cur >= 0) {
        float* pp = &pooled[cur * DIM + lane4 * 4];
        atomicAdd(pp + 0, a0); atomicAdd(pp + 1, a1);
        atomicAdd(pp + 2, a2); atomicAdd(pp + 3, a3);
    }
}

// ---------------- head ----------------

__global__ void mlp_head(const float* __restrict__ pooled, const float* __restrict__ Wm,
                         const float* __restrict__ bm, float* __restrict__ out) {
    int t = blockIdx.x * blockDim.x + threadIdx.x;
    if (t >= N_GRAPHS * N_OUT) return;
    int b = t / N_OUT;
    int o = t % N_OUT;
    float acc = bm[o];
    #pragma unroll 8
    for (int k = 0; k < DIM; ++k) acc += pooled[b * DIM + k] * Wm[k * N_OUT + o];
    out[t] = acc;
}

// ---------------- launch ----------------

extern "C" void kernel_launch(void* const* d_in, const int* in_sizes, int n_in,
                              void* d_out, int out_size, void* d_ws, size_t ws_size,
                              hipStream_t stream) {
    const float* x     = (const float*)d_in[0];
    const int*   ei    = (const int*)d_in[1];
    const int*   batch = (const int*)d_in[2];
    const float* Ws    = (const float*)d_in[3];
    const float* bs    = (const float*)d_in[4];
    const float* Wm    = (const float*)d_in[5];
    const float* bm    = (const float*)d_in[6];
    float* out = (float*)d_out;

    // workspace carve-up (16B aligned regions; cnt+cursor+rangeCur adjacent for one memset)
    char* p = (char*)d_ws;
    int*          cnt      = (int*)p;          p += N_NODES * 4;
    int*          cursor   = (int*)p;          p += N_NODES * 4;
    int*          rangeCur = (int*)p;          p += 16 * 4;
    float*        dinv     = (float*)p;        p += N_NODES * 4;
    int*          csr_off  = (int*)p;          p += (N_NODES + 16) * 4;
    int*          bsum     = (int*)p;          p += 128 * 4;
    _Float16*     wt       = (_Float16*)p;     p += (size_t)N_LAYERS * DIM * DIM * 2;
    int*          csr_src  = (int*)p;          p += (size_t)N_EDGES * 4;
    int2*         staging  = (int2*)p;         p += (size_t)NXCD * R_EST * 8;
    _Float16*     bufA     = (_Float16*)p;     p += (size_t)N_NODES * DIM * 2;  // hw' (dinv-prescaled)
    _Float16*     bufB     = (_Float16*)p;     p += (size_t)N_NODES * DIM * 2;  // h
    float*        pooled   = (float*)p;        p += N_GRAPHS * DIM * 4;

    const int nnode_blk = (N_NODES + 255) / 256;

    hipMemsetAsync(cnt, 0, N_NODES * 8 + 16 * 4, stream);  // cnt + cursor + rangeCur
    hipMemsetAsync(pooled, 0, N_GRAPHS * DIM * 4, stream);

    bucket_edges<<<N_EDGES / BE, 256, 0, stream>>>(ei, rangeCur, staging);
    wt_prep<<<(N_LAYERS * DIM * 32 + 255) / 256, 256, 0, stream>>>(Ws, wt);

    hist_pinned<<<NXCD * RK, 256, 0, stream>>>(staging, rangeCur, cnt);

    scan1<<<N_SCAN_BLKS, 256, 0, stream>>>(cnt, csr_off, bsum, dinv);
    scan2<<<1, 128, 0, stream>>>(bsum);
    scan3<<<nnode_blk, 256, 0, stream>>>(csr_off, bsum);

    fill_pinned<<<NXCD * RK, 256, 0, stream>>>(staging, rangeCur, csr_off, cursor, csr_src);

    const int gather_grid = (N_NODES * 64 + 255) / 256;  // one wave per node
    for (int l = 0; l < N_LAYERS; ++l) {
        if (l == 0) gemm_mfma<float><<<GEMM_GRID, 256, 0, stream>>>(x, wt, dinv, bufA);
        else        gemm_mfma<_Float16><<<GEMM_GRID, 256, 0, stream>>>(bufB, wt + (size_t)l * DIM * DIM, dinv, bufA);
        gather_agg<<<gather_grid, 256, 0, stream>>>(bufA, dinv, csr_off, csr_src, bs + l * DIM, bufB);
    }

    pool_chunk<<<(N_NODES + PCHUNK - 1) / PCHUNK, 256, 0, stream>>>(bufB, batch, pooled);
    mlp_head<<<(N_GRAPHS * N_OUT + 255) / 256, 256, 0, stream>>>(pooled, Wm, bm, out);
}